// Round 13
// baseline (33.475 us; speedup 1.0000x reference)
//
#include <hip/hip_runtime.h>

// DQSN forward (v10): R12's verified body, 2-way H-split for residency.
//
// out[b,o] = sum_h W2[o,h] * A[b,h] + b2[o] * (1 - 2^-16)
// A depends only on n = first j in 1..16 with fp32-cumsum_j(I) >= 1
// (hard reset to exactly 0.0 -> exactly periodic spike train, period n).
// n = med3(ceil(rcp(I)), 0, 17); provably equals the fp32-cumsum crossing
// outside the |r - nearest-int| < GUARD band; in-band elements (P ~ 1e-4)
// fall back to the exact 16-step simulation (bit-faithful decisions).
//
// Stage 1: block g handles rows (g>>1)*8..+8, h-half (g&1); writes 16
// partial sums to d_ws. Stage 2: combine = partial_lo + partial_hi + bias
// (fixed association -> deterministic).

constexpr int TSTEPS = 16;
constexpr int NB = 8;
constexpr float GUARD = 4e-5f;
constexpr float GTHR  = 0.5f - GUARD;

__global__ __launch_bounds__(256) void dqsn_stage1(
    const float* __restrict__ x,
    const float* __restrict__ W1,
    const float* __restrict__ b1,
    const float* __restrict__ W2,
    float* __restrict__ ws,
    int B, int H)
{
    const int tid  = threadIdx.x;
    const int lane = tid & 63;
    const int g    = blockIdx.x;
    const int b0   = (g >> 1) * NB;
    const int half = g & 1;
    const int hbeg = half * (H >> 1);
    const int hend = hbeg + (H >> 1);

    // per-lane A(n) table: lane l (1..16) holds A for period n=l.
    float tval = 0.0f;
    if (lane >= 1 && lane <= TSTEPS) {
        unsigned mm = 0;
        for (int k = lane; k <= TSTEPS; k += lane) mm |= 1u << (k - 1);
        tval = (float)mm * 0x1p-16f;   // exact: mm < 2^17
    }
    const int table_reg = __float_as_int(tval);

    float xs0[NB], xs1[NB], xs2[NB], xs3[NB];
#pragma unroll
    for (int i = 0; i < NB; ++i) {
        const int bi = (b0 + i < B) ? (b0 + i) : (B - 1);
        xs0[i] = x[bi * 4 + 0];
        xs1[i] = x[bi * 4 + 1];
        xs2[i] = x[bi * 4 + 2];
        xs3[i] = x[bi * 4 + 3];
    }

    float acc0[NB], acc1[NB];
#pragma unroll
    for (int i = 0; i < NB; ++i) { acc0[i] = 0.0f; acc1[i] = 0.0f; }

    // tight runtime loop, minimal live-set (R12's verified shape)
    for (int h = hbeg + tid; h < hend; h += 256) {
        const float4 w1 = *reinterpret_cast<const float4*>(W1 + (size_t)h * 4);
        const float bb  = b1[h];
        const float w2a = W2[h];
        const float w2b = W2[H + h];

#pragma unroll
        for (int i = 0; i < NB; ++i) {
            const float I = fmaf(xs0[i], w1.x,
                            fmaf(xs1[i], w1.y,
                            fmaf(xs2[i], w1.z,
                            fmaf(xs3[i], w1.w, bb))));

            const float r = __builtin_amdgcn_rcpf(I);
            const float c = __builtin_ceilf(r);
            int idx = (int)__builtin_amdgcn_fmed3f(c, 0.0f, 17.0f) << 2;

            // per-element guard: near a breakpoint -> exact 16-step fallback
            if (__builtin_expect(
                    (unsigned long long)__ballot(fabsf((r - c) + 0.5f) > GTHR), 0)) {
                float v = 0.0f;
                int cnt = 0;
#pragma unroll
                for (int t = 0; t < TSTEPS; ++t) {
                    v += I;
                    cnt += (v < 1.0f) ? 1 : 0;
                }
                idx = (cnt + 1) << 2;          // exact for all lanes
            }

            const float A = __int_as_float(__builtin_amdgcn_ds_bpermute(idx, table_reg));
            acc0[i] = fmaf(A, w2a, acc0[i]);
            acc1[i] = fmaf(A, w2b, acc1[i]);
        }
    }

    // ---- value-halving wave reduction (verified in R10/R12) ----
    float v[16];
#pragma unroll
    for (int i = 0; i < NB; ++i) {
        v[2 * i + 0] = acc0[i];
        v[2 * i + 1] = acc1[i];
    }

    {   // off=32: 16 -> 8 values
        const bool up = (lane & 32) != 0;
#pragma unroll
        for (int k = 0; k < 8; ++k) {
            const float mine = up ? v[k] : v[k + 8];
            const float recv = __shfl_xor(mine, 32, 64);
            v[k] = (up ? v[k + 8] : v[k]) + recv;
        }
    }
    {   // off=16: 8 -> 4
        const bool up = (lane & 16) != 0;
#pragma unroll
        for (int k = 0; k < 4; ++k) {
            const float mine = up ? v[k] : v[k + 4];
            const float recv = __shfl_xor(mine, 16, 64);
            v[k] = (up ? v[k + 4] : v[k]) + recv;
        }
    }
    {   // off=8: 4 -> 2
        const bool up = (lane & 8) != 0;
#pragma unroll
        for (int k = 0; k < 2; ++k) {
            const float mine = up ? v[k] : v[k + 2];
            const float recv = __shfl_xor(mine, 8, 64);
            v[k] = (up ? v[k + 2] : v[k]) + recv;
        }
    }
    {   // off=4: 2 -> 1
        const bool up = (lane & 4) != 0;
        const float mine = up ? v[0] : v[1];
        const float recv = __shfl_xor(mine, 4, 64);
        v[0] = (up ? v[1] : v[0]) + recv;
    }
    float tot = v[0];
    tot += __shfl_xor(tot, 1, 64);
    tot += __shfl_xor(tot, 2, 64);

    __shared__ float red[4][16];
    if ((lane & 3) == 0) red[tid >> 6][lane >> 2] = tot;
    __syncthreads();

    if (tid < 16) {
        const float s = (red[0][tid] + red[1][tid]) + (red[2][tid] + red[3][tid]);
        ws[(size_t)g * 16 + tid] = s;   // partial, no bias
    }
}

__global__ __launch_bounds__(256) void dqsn_combine(
    const float* __restrict__ ws,
    const float* __restrict__ b2,
    float* __restrict__ out,
    int B)
{
    const int i = blockIdx.x * 256 + threadIdx.x;   // i = b*2 + o
    if (i >= B * 2) return;
    const int b  = i >> 1;
    const int o  = i & 1;
    const int rg = b >> 3;
    const int j  = ((b & 7) << 1) | o;
    const float s = ws[(size_t)rg * 32 + j] + ws[(size_t)rg * 32 + 16 + j];
    out[i] = s + b2[o] * (1.0f - 0x1p-16f);
}

extern "C" void kernel_launch(void* const* d_in, const int* in_sizes, int n_in,
                              void* d_out, int out_size, void* d_ws, size_t ws_size,
                              hipStream_t stream) {
    const float* x  = (const float*)d_in[0];
    const float* W1 = (const float*)d_in[1];
    const float* b1 = (const float*)d_in[2];
    const float* W2 = (const float*)d_in[3];
    const float* b2 = (const float*)d_in[4];
    float* out = (float*)d_out;
    float* ws  = (float*)d_ws;

    const int B = in_sizes[0] / 4;   // 16384
    const int H = in_sizes[2];       // 4096

    const int grid1 = ((B + NB - 1) / NB) * 2;       // 4096
    dqsn_stage1<<<grid1, 256, 0, stream>>>(x, W1, b1, W2, ws, B, H);

    const int grid2 = (B * 2 + 255) / 256;           // 128
    dqsn_combine<<<grid2, 256, 0, stream>>>(ws, b2, out, B);
}